// Round 1
// baseline (345.199 us; speedup 1.0000x reference)
//
#include <hip/hip_runtime.h>

typedef _Float16 f16x8 __attribute__((ext_vector_type(8)));
typedef _Float16 f16x4 __attribute__((ext_vector_type(4)));
typedef float    f32x4 __attribute__((ext_vector_type(4)));
typedef int      i32x4 __attribute__((ext_vector_type(4)));

#define S_LEN 2048
#define D_KH  64
#define NBH   32                       // B*H
#define QTILE 16
#define NBLK  (NBH * (S_LEN / QTILE))  // 4096

__device__ __forceinline__ f16x8 cvt8(const float4 a, const float4 b) {
  f16x8 r;
  r[0] = (_Float16)a.x; r[1] = (_Float16)a.y;
  r[2] = (_Float16)a.z; r[3] = (_Float16)a.w;
  r[4] = (_Float16)b.x; r[5] = (_Float16)b.y;
  r[6] = (_Float16)b.z; r[7] = (_Float16)b.w;
  return r;
}

__global__ __launch_bounds__(256) void sdpa_probs_kernel(
    const float* __restrict__ q, const float* __restrict__ kmat,
    const int* __restrict__ mask, float* __restrict__ out) {
  // XCD-aware swizzle: 4096 blocks, 8 XCDs -> 512 consecutive per XCD
  // (keeps one head's 512 KiB K panel hot in a single XCD L2)
  const int bid = (int)blockIdx.x;
  const int nb  = (bid & 7) * (NBLK / 8) + (bid >> 3);
  const int bh  = nb >> 7;    // 0..31
  const int qt  = nb & 127;   // q-tile index, 0..127

  __shared__ _Float16 sc[QTILE][S_LEN];  // 64 KiB score strip (f16)

  const int tid   = (int)threadIdx.x;
  const int w     = tid >> 6;   // wave 0..3
  const int l     = tid & 63;   // lane
  const int lo    = l & 15;
  const int g     = l >> 4;     // 0..3 (K-chunk group)
  const int dbase = g << 3;

  const size_t qk_bh = (size_t)bh * S_LEN * D_KH;

  // ---- A fragments: q rows (qt*16 + lo), scaled by 1/sqrt(64) = 0.125 ----
  f16x8 a0, a1;
  {
    const float* qp = q + qk_bh + (size_t)(qt * QTILE + lo) * D_KH;
    float4 t0 = *(const float4*)(qp + dbase);
    float4 t1 = *(const float4*)(qp + dbase + 4);
    float4 t2 = *(const float4*)(qp + dbase + 32);
    float4 t3 = *(const float4*)(qp + dbase + 36);
    const float s = 0.125f;
    t0.x *= s; t0.y *= s; t0.z *= s; t0.w *= s;
    t1.x *= s; t1.y *= s; t1.z *= s; t1.w *= s;
    t2.x *= s; t2.y *= s; t2.z *= s; t2.w *= s;
    t3.x *= s; t3.y *= s; t3.z *= s; t3.w *= s;
    a0 = cvt8(t0, t1);   // d = dbase..dbase+7   (covers k-dim 0..31 across lanes)
    a1 = cvt8(t2, t3);   // d = 32+dbase..+7     (covers k-dim 32..63)
  }

  // ---- Phase 1: scores via f16 MFMA, each wave owns a 512-key strip ----
  const float* kb = kmat + qk_bh;
  #pragma unroll 4
  for (int kt = 0; kt < 32; ++kt) {
    const int kcol = (w << 9) + (kt << 4) + lo;         // key index
    const float* kp = kb + (size_t)kcol * D_KH + dbase;
    const float4 b00 = *(const float4*)(kp);
    const float4 b01 = *(const float4*)(kp + 4);
    const float4 b10 = *(const float4*)(kp + 32);
    const float4 b11 = *(const float4*)(kp + 36);
    const f16x8 b0 = cvt8(b00, b01);
    const f16x8 b1 = cvt8(b10, b11);
    f32x4 acc = {0.f, 0.f, 0.f, 0.f};
    acc = __builtin_amdgcn_mfma_f32_16x16x32_f16(a0, b0, acc, 0, 0, 0);
    acc = __builtin_amdgcn_mfma_f32_16x16x32_f16(a1, b1, acc, 0, 0, 0);
    // D layout: row = 4*g + r, col = lo. XOR-swizzle col bit4 by (row>>2)=g
    // -> write banks spread across all 32 (conflict-free, verified by hand).
    const int phys = kcol ^ (g << 4);
    #pragma unroll
    for (int r = 0; r < 4; ++r)
      sc[(g << 2) + r][phys] = (_Float16)acc[r];
  }
  __syncthreads();

  // ---- Phase 2: per-row softmax; wave w owns rows 4w..4w+3 ----
  const size_t obh = (size_t)bh * S_LEN * S_LEN;
  #pragma unroll 1
  for (int ri = 0; ri < 4; ++ri) {
    const int row = (w << 2) + ri;          // row>>2 == w (matches write swizzle)
    const size_t orow = obh + (size_t)(qt * QTILE + row) * S_LEN;
    const int* mrow = mask + orow;
    float sv[32];
    #pragma unroll
    for (int i = 0; i < 8; ++i) {
      const int col  = (i << 8) + (l << 2);
      const int phys = col ^ (w << 4);
      const f16x4 h  = *(const f16x4*)&sc[row][phys];
      const i32x4 mv = __builtin_nontemporal_load((const i32x4*)(mrow + col));
      sv[(i << 2) + 0] = mv.x ? -1.0e9f : (float)h[0];
      sv[(i << 2) + 1] = mv.y ? -1.0e9f : (float)h[1];
      sv[(i << 2) + 2] = mv.z ? -1.0e9f : (float)h[2];
      sv[(i << 2) + 3] = mv.w ? -1.0e9f : (float)h[3];
    }
    float mx = -3.0e38f;
    #pragma unroll
    for (int i = 0; i < 32; ++i) mx = fmaxf(mx, sv[i]);
    #pragma unroll
    for (int off = 32; off > 0; off >>= 1)
      mx = fmaxf(mx, __shfl_xor(mx, off, 64));
    float sum = 0.f;
    #pragma unroll
    for (int i = 0; i < 32; ++i) { sv[i] = __expf(sv[i] - mx); sum += sv[i]; }
    #pragma unroll
    for (int off = 32; off > 0; off >>= 1)
      sum += __shfl_xor(sum, off, 64);
    const float inv = 1.0f / sum;
    float* op = out + orow;
    #pragma unroll
    for (int i = 0; i < 8; ++i) {
      const int col = (i << 8) + (l << 2);
      f32x4 o = { sv[(i << 2) + 0] * inv, sv[(i << 2) + 1] * inv,
                  sv[(i << 2) + 2] * inv, sv[(i << 2) + 3] * inv };
      __builtin_nontemporal_store(o, (f32x4*)(op + col));
    }
  }
}

extern "C" void kernel_launch(void* const* d_in, const int* in_sizes, int n_in,
                              void* d_out, int out_size, void* d_ws, size_t ws_size,
                              hipStream_t stream) {
  const float* q    = (const float*)d_in[0];
  const float* kmat = (const float*)d_in[1];
  // d_in[2] = v, unused by the reference (it stops at the softmax)
  const int*   mask = (const int*)d_in[3];
  float*       out  = (float*)d_out;
  sdpa_probs_kernel<<<dim3(NBLK), dim3(256), 0, stream>>>(q, kmat, mask, out);
}

// Round 2
// 238.756 us; speedup vs baseline: 1.4458x; 1.4458x over previous
//
#include <hip/hip_runtime.h>

typedef _Float16 f16x8 __attribute__((ext_vector_type(8)));
typedef _Float16 f16x4 __attribute__((ext_vector_type(4)));
typedef float    f32x4 __attribute__((ext_vector_type(4)));
typedef int      i32x4 __attribute__((ext_vector_type(4)));

#define S_LEN 2048
#define D_KH  64
#define NBH   32                       // B*H
#define QTILE 16
#define NBLK  (NBH * (S_LEN / QTILE))  // 4096
#define THREADS 512                    // 8 waves/block
#define QK_ELEMS (NBH * S_LEN * D_KH)  // 4194304 elements per tensor

__device__ __forceinline__ f16x8 cvt8(const float4 a, const float4 b) {
  f16x8 r;
  r[0] = (_Float16)a.x; r[1] = (_Float16)a.y;
  r[2] = (_Float16)a.z; r[3] = (_Float16)a.w;
  r[4] = (_Float16)b.x; r[5] = (_Float16)b.y;
  r[6] = (_Float16)b.z; r[7] = (_Float16)b.w;
  return r;
}

// Prep: K -> f16, q -> f16 pre-scaled by 1/sqrt(64). Halves phase-1 L2 bytes
// and removes per-block cvt VALU from the main kernel's K-loop.
__global__ __launch_bounds__(256) void cvt_qk_kernel(
    const float* __restrict__ q, const float* __restrict__ kmat,
    _Float16* __restrict__ qh, _Float16* __restrict__ kh) {
  const long long idx = ((long long)blockIdx.x * 256 + threadIdx.x) * 8;
  float4 q0 = *(const float4*)(q + idx);
  float4 q1 = *(const float4*)(q + idx + 4);
  const float s = 0.125f;
  q0.x *= s; q0.y *= s; q0.z *= s; q0.w *= s;
  q1.x *= s; q1.y *= s; q1.z *= s; q1.w *= s;
  *(f16x8*)(qh + idx) = cvt8(q0, q1);
  const float4 k0 = *(const float4*)(kmat + idx);
  const float4 k1 = *(const float4*)(kmat + idx + 4);
  *(f16x8*)(kh + idx) = cvt8(k0, k1);
}

__device__ __forceinline__ void softmax_row(float sv[32], const int l,
                                            float* __restrict__ op) {
  float mx = -3.0e38f;
  #pragma unroll
  for (int i = 0; i < 32; ++i) mx = fmaxf(mx, sv[i]);
  #pragma unroll
  for (int off = 32; off > 0; off >>= 1)
    mx = fmaxf(mx, __shfl_xor(mx, off, 64));
  float sum = 0.f;
  #pragma unroll
  for (int i = 0; i < 32; ++i) { sv[i] = __expf(sv[i] - mx); sum += sv[i]; }
  #pragma unroll
  for (int off = 32; off > 0; off >>= 1)
    sum += __shfl_xor(sum, off, 64);
  const float inv = 1.0f / sum;
  #pragma unroll
  for (int i = 0; i < 8; ++i) {
    const int col = (i << 8) + (l << 2);
    f32x4 o = { sv[4 * i + 0] * inv, sv[4 * i + 1] * inv,
                sv[4 * i + 2] * inv, sv[4 * i + 3] * inv };
    __builtin_nontemporal_store(o, (f32x4*)(op + col));
  }
}

template <bool F16>
__global__ __launch_bounds__(THREADS, 4) void sdpa_probs_kernel(
    const float* __restrict__ qf, const float* __restrict__ kf,
    const _Float16* __restrict__ qh, const _Float16* __restrict__ kh,
    const int* __restrict__ mask, float* __restrict__ out) {
  // XCD-aware swizzle: 512 consecutive nb per XCD -> 4 heads' K panels
  // (2 MiB f16) stay hot in one XCD L2.
  const int bid = (int)blockIdx.x;
  const int nb  = (bid & 7) * (NBLK / 8) + (bid >> 3);
  const int bh  = nb >> 7;    // 0..31
  const int qt  = nb & 127;   // q-tile index

  __shared__ _Float16 sc[QTILE][S_LEN];  // 64 KiB score strip

  const int tid   = (int)threadIdx.x;
  const int w     = tid >> 6;   // wave 0..7
  const int l     = tid & 63;
  const int lo    = l & 15;
  const int g     = l >> 4;     // 0..3
  const int dbase = g << 3;

  const size_t qk_bh = (size_t)bh * S_LEN * D_KH;
  const size_t obh   = (size_t)bh * S_LEN * S_LEN;

  const int rowA = w << 1, rowB = rowA + 1;   // wave w owns rows 2w, 2w+1
  const size_t orowA = obh + (size_t)(qt * QTILE + rowA) * S_LEN;
  const size_t orowB = obh + (size_t)(qt * QTILE + rowB) * S_LEN;

  // ---- Early mask prefetch (row A): HBM latency hides under phase 1 ----
  i32x4 mA[8];
  {
    const int* mrow = mask + orowA;
    #pragma unroll
    for (int i = 0; i < 8; ++i)
      mA[i] = __builtin_nontemporal_load((const i32x4*)(mrow + (i << 8) + (l << 2)));
  }

  // ---- A fragments: q rows, pre-scaled ----
  f16x8 a0, a1;
  if constexpr (F16) {
    const _Float16* qp = qh + qk_bh + (size_t)(qt * QTILE + lo) * D_KH + dbase;
    a0 = *(const f16x8*)qp;
    a1 = *(const f16x8*)(qp + 32);
  } else {
    const float* qp = qf + qk_bh + (size_t)(qt * QTILE + lo) * D_KH;
    float4 t0 = *(const float4*)(qp + dbase);
    float4 t1 = *(const float4*)(qp + dbase + 4);
    float4 t2 = *(const float4*)(qp + dbase + 32);
    float4 t3 = *(const float4*)(qp + dbase + 36);
    const float s = 0.125f;
    t0.x *= s; t0.y *= s; t0.z *= s; t0.w *= s;
    t1.x *= s; t1.y *= s; t1.z *= s; t1.w *= s;
    t2.x *= s; t2.y *= s; t2.z *= s; t2.w *= s;
    t3.x *= s; t3.y *= s; t3.z *= s; t3.w *= s;
    a0 = cvt8(t0, t1);
    a1 = cvt8(t2, t3);
  }

  // ---- Phase 1: scores via f16 MFMA, each wave owns a 256-key strip ----
  #pragma unroll 4
  for (int kt = 0; kt < 16; ++kt) {
    const int kcol = (w << 8) + (kt << 4) + lo;
    f16x8 b0, b1;
    if constexpr (F16) {
      const _Float16* kp = kh + qk_bh + (size_t)kcol * D_KH + dbase;
      b0 = *(const f16x8*)kp;
      b1 = *(const f16x8*)(kp + 32);
    } else {
      const float* kp = kf + qk_bh + (size_t)kcol * D_KH + dbase;
      b0 = cvt8(*(const float4*)(kp), *(const float4*)(kp + 4));
      b1 = cvt8(*(const float4*)(kp + 32), *(const float4*)(kp + 36));
    }
    f32x4 acc = {0.f, 0.f, 0.f, 0.f};
    acc = __builtin_amdgcn_mfma_f32_16x16x32_f16(a0, b0, acc, 0, 0, 0);
    acc = __builtin_amdgcn_mfma_f32_16x16x32_f16(a1, b1, acc, 0, 0, 0);
    // D layout: row = 4g+r, col = lo. XOR-swizzle col bit4 by g -> 32 banks,
    // 2 lanes each (free).
    const int phys = kcol ^ (g << 4);
    #pragma unroll
    for (int r = 0; r < 4; ++r)
      sc[(g << 2) + r][phys] = (_Float16)acc[r];
  }

  // Keep prefetched masks live across phase 1 (prevent load sinking).
  #pragma unroll
  for (int i = 0; i < 8; ++i) asm volatile("" :: "v"(mA[i]));
  __syncthreads();

  // ---- Phase 2: softmax. rowA>>2 == rowB>>2 == w>>1 -> same read swizzle.
  const int physx = (w >> 1) << 4;
  float sv[32];
  #pragma unroll
  for (int i = 0; i < 8; ++i) {
    const int col = (i << 8) + (l << 2);
    const f16x4 h = *(const f16x4*)&sc[rowA][col ^ physx];
    sv[4 * i + 0] = mA[i].x ? -1.0e9f : (float)h[0];
    sv[4 * i + 1] = mA[i].y ? -1.0e9f : (float)h[1];
    sv[4 * i + 2] = mA[i].z ? -1.0e9f : (float)h[2];
    sv[4 * i + 3] = mA[i].w ? -1.0e9f : (float)h[3];
  }
  // Issue row-B masks now; latency hides under row-A softmax/store.
  i32x4 mB[8];
  {
    const int* mrow = mask + orowB;
    #pragma unroll
    for (int i = 0; i < 8; ++i)
      mB[i] = __builtin_nontemporal_load((const i32x4*)(mrow + (i << 8) + (l << 2)));
  }
  softmax_row(sv, l, out + orowA);

  #pragma unroll
  for (int i = 0; i < 8; ++i) {
    const int col = (i << 8) + (l << 2);
    const f16x4 h = *(const f16x4*)&sc[rowB][col ^ physx];
    sv[4 * i + 0] = mB[i].x ? -1.0e9f : (float)h[0];
    sv[4 * i + 1] = mB[i].y ? -1.0e9f : (float)h[1];
    sv[4 * i + 2] = mB[i].z ? -1.0e9f : (float)h[2];
    sv[4 * i + 3] = mB[i].w ? -1.0e9f : (float)h[3];
  }
  softmax_row(sv, l, out + orowB);
}

extern "C" void kernel_launch(void* const* d_in, const int* in_sizes, int n_in,
                              void* d_out, int out_size, void* d_ws, size_t ws_size,
                              hipStream_t stream) {
  const float* q    = (const float*)d_in[0];
  const float* kmat = (const float*)d_in[1];
  // d_in[2] = v, unused (reference stops at softmax)
  const int*   mask = (const int*)d_in[3];
  float*       out  = (float*)d_out;

  const size_t need = (size_t)QK_ELEMS * 2 * sizeof(_Float16);  // q̂ + K̂ f16
  if (ws_size >= need) {
    _Float16* qh = (_Float16*)d_ws;
    _Float16* kh = qh + QK_ELEMS;
    cvt_qk_kernel<<<dim3(QK_ELEMS / 8 / 256), dim3(256), 0, stream>>>(q, kmat, qh, kh);
    sdpa_probs_kernel<true><<<dim3(NBLK), dim3(THREADS), 0, stream>>>(
        nullptr, nullptr, qh, kh, mask, out);
  } else {
    sdpa_probs_kernel<false><<<dim3(NBLK), dim3(THREADS), 0, stream>>>(
        q, kmat, nullptr, nullptr, mask, out);
  }
}